// Round 5
// baseline (3301.554 us; speedup 1.0000x reference)
//
#include <hip/hip_runtime.h>
#include <hip/hip_bf16.h>

// Decoder_75720273428908 — transformerCPI decoder, round 5.
// B=16, T=512, S=1024, H=256, NH=8, D=32, PF=512, L=2, A=64.
// Inputs FP32 (proved rounds 1-3). OUTPUTS FP32 (round-4 deduction: error
// 0.2009 == max|pooled| == packed-bf16 pooled data invading fp32 label words
// 16..31 when outputs were written as bf16; harness doc: out dtype = reference
// output dtype = float32).
// Out layout (fp32 elems): label[32] @0, pooled[4096] @32, att[67108864] @4128.
// WS: x[2M] | sub[2M] | qb[2M] | kb[4M] | vb[4M] floats = 56 MiB.
//   ob aliases qb (each block reads its Q elems to LDS before writing same addrs).
//   ffm aliases kb; nrm/pld alias vb (free after layer loop).

typedef __hip_bfloat16 bf16;

#define AROWS 8

// ---------------- GEMM: C[M,N] = A[M,K] @ W[K,N] + bias, optional ReLU -----
// 64x64 tile, 256 threads (16x16), 4x4 microtile, K-tile 16. All fp32.
template <bool RELU>
__global__ __launch_bounds__(256) void gemm_bias(
    const float* __restrict__ A, const float* __restrict__ W,
    const float* __restrict__ bias, float* __restrict__ C,
    int M, int N, int K)
{
  __shared__ float As[16][68];
  __shared__ float Ws[16][68];
  const int tid = threadIdx.x;
  const int tx = tid & 15, ty = tid >> 4;
  const int m0 = blockIdx.x * 64, n0 = blockIdx.y * 64;
  float acc[4][4] = {};
  for (int k0 = 0; k0 < K; k0 += 16) {
    for (int i = tid; i < 1024; i += 256) {
      int mm = i >> 4, kk = i & 15;
      As[kk][mm] = A[(size_t)(m0 + mm) * K + k0 + kk];
    }
    for (int i = tid; i < 1024; i += 256) {
      int kk = i >> 6, nn = i & 63;
      Ws[kk][nn] = W[(size_t)(k0 + kk) * N + n0 + nn];
    }
    __syncthreads();
#pragma unroll
    for (int kk = 0; kk < 16; kk++) {
      float4 a4 = *(const float4*)&As[kk][ty * 4];
      float4 w4 = *(const float4*)&Ws[kk][tx * 4];
      acc[0][0] += a4.x * w4.x; acc[0][1] += a4.x * w4.y; acc[0][2] += a4.x * w4.z; acc[0][3] += a4.x * w4.w;
      acc[1][0] += a4.y * w4.x; acc[1][1] += a4.y * w4.y; acc[1][2] += a4.y * w4.z; acc[1][3] += a4.y * w4.w;
      acc[2][0] += a4.z * w4.x; acc[2][1] += a4.z * w4.y; acc[2][2] += a4.z * w4.z; acc[2][3] += a4.z * w4.w;
      acc[3][0] += a4.w * w4.x; acc[3][1] += a4.w * w4.y; acc[3][2] += a4.w * w4.z; acc[3][3] += a4.w * w4.w;
    }
    __syncthreads();
  }
  for (int i = 0; i < 4; i++) {
    int m = m0 + ty * 4 + i;
    for (int j = 0; j < 4; j++) {
      int n = n0 + tx * 4 + j;
      float v = acc[i][j] + bias[n];
      if (RELU) v = fmaxf(v, 0.f);
      C[(size_t)m * N + n] = v;
    }
  }
}

// ---------------- Fused attention (per b,h,8 q-rows) -----------------------
// Q,K,V in [B, T, NH, D] layout (i.e. [rows, 256] with col = h*32+d).
// O in same layout; O may alias Q (each block reads exactly the Q elements it
// later writes; no cross-block overlap).
__global__ __launch_bounds__(256) void attn_kernel(
    const float* __restrict__ Q, const float* __restrict__ K,
    const float* __restrict__ V, float* __restrict__ O,
    float* __restrict__ att_out, int Tq, int Tk, float inv_scale)
{
  extern __shared__ float smem[];
  const int SCP = Tk + 4;              // score row stride (float4-aligned, bank-skewed)
  float* sc = smem;                    // [8][SCP]
  float* kv = sc + 8 * SCP;            // 2304 floats: K as [64][36] or V^T as [32][68]
  float* qs = kv + 2304;               // [8][36]
  const int b = blockIdx.z, h = blockIdx.y, q0 = blockIdx.x * AROWS;
  const int tid = threadIdx.x;

  {  // load 8 Q rows
    int r = tid >> 5, d = tid & 31;
    qs[r * 36 + d] = Q[(((size_t)b * Tq + q0 + r) * 8 + h) * 32 + d];
  }
  // ---- scores ----
  for (int kt = 0; kt < Tk; kt += 64) {
    for (int i = tid; i < 2048; i += 256) {
      int kk = i >> 5, d = i & 31;
      kv[kk * 36 + d] = K[(((size_t)b * Tk + kt + kk) * 8 + h) * 32 + d];
    }
    __syncthreads();
#pragma unroll
    for (int pp = 0; pp < 2; pp++) {
      int p = tid + pp * 256;
      int r = p & 7, kk = p >> 3;
      const float4* qv = (const float4*)(qs + r * 36);
      const float4* kq = (const float4*)(kv + kk * 36);
      float s = 0.f;
#pragma unroll
      for (int d4 = 0; d4 < 8; d4++) {
        float4 a = qv[d4], bb = kq[d4];
        s += a.x * bb.x + a.y * bb.y + a.z * bb.z + a.w * bb.w;
      }
      sc[r * SCP + kt + kk] = s * inv_scale;
    }
    __syncthreads();
  }
  // ---- softmax: 32 threads per row ----
  {
    int r = tid >> 5, j = tid & 31;
    float m = -1e30f;
    for (int k = j; k < Tk; k += 32) m = fmaxf(m, sc[r * SCP + k]);
    for (int off = 16; off > 0; off >>= 1) m = fmaxf(m, __shfl_xor(m, off, 32));
    float sum = 0.f;
    for (int k = j; k < Tk; k += 32) {
      float e = __expf(sc[r * SCP + k] - m);
      sc[r * SCP + k] = e; sum += e;
    }
    for (int off = 16; off > 0; off >>= 1) sum += __shfl_xor(sum, off, 32);
    float inv = 1.f / sum;
    for (int k = j; k < Tk; k += 32) sc[r * SCP + k] *= inv;
  }
  __syncthreads();
  // ---- optional att output (fp32, [B,NH,Tq,Tk], Tk==1024 only) ----
  if (att_out) {
    for (int i = tid; i < AROWS * 1024; i += 256) {
      int r = i >> 10, k = i & 1023;
      att_out[(((size_t)(b * 8 + h) * Tq) + q0 + r) * 1024 + k] = sc[r * SCP + k];
    }
  }
  // ---- O = P @ V (V^T tiles of [32 d][64 k] in LDS) ----
  const int r = tid >> 5, d = tid & 31;
  float acc = 0.f;
  for (int kt = 0; kt < Tk; kt += 64) {
    __syncthreads();
    for (int i = tid; i < 2048; i += 256) {
      int kk = i >> 5, dd = i & 31;
      kv[dd * 68 + kk] = V[(((size_t)b * Tk + kt + kk) * 8 + h) * 32 + dd];
    }
    __syncthreads();
    const float4* pv = (const float4*)(sc + r * SCP + kt);
    const float4* vv = (const float4*)(kv + d * 68);
#pragma unroll
    for (int k4 = 0; k4 < 16; k4++) {
      float4 p = pv[k4], vx = vv[k4];
      acc += p.x * vx.x + p.y * vx.y + p.z * vx.z + p.w * vx.w;
    }
  }
  O[(((size_t)b * Tq + q0 + r) * 8 + h) * 32 + d] = acc;
}

// ---------------- residual + LayerNorm (in place on x) ---------------------
__global__ __launch_bounds__(256) void residual_ln(
    float* __restrict__ x, const float* __restrict__ sub,
    const float* __restrict__ g, const float* __restrict__ bi)
{
  __shared__ float red[4];
  const size_t row = blockIdx.x;
  const int tid = threadIdx.x;
  float v = x[row * 256 + tid] + sub[row * 256 + tid];
  float s = v;
  for (int off = 32; off > 0; off >>= 1) s += __shfl_xor(s, off, 64);
  if ((tid & 63) == 0) red[tid >> 6] = s;
  __syncthreads();
  float mean = (red[0] + red[1] + red[2] + red[3]) * (1.f / 256.f);
  float d = v - mean;
  float s2 = d * d;
  for (int off = 32; off > 0; off >>= 1) s2 += __shfl_xor(s2, off, 64);
  __syncthreads();
  if ((tid & 63) == 0) red[tid >> 6] = s2;
  __syncthreads();
  float var = (red[0] + red[1] + red[2] + red[3]) * (1.f / 256.f);
  x[row * 256 + tid] = d * rsqrtf(var + 1e-5f) * g[tid] + bi[tid];
}

// ---------------- row norms ------------------------------------------------
__global__ __launch_bounds__(256) void row_norm(
    const float* __restrict__ x, float* __restrict__ nrm)
{
  __shared__ float red[4];
  const size_t row = blockIdx.x;
  const int tid = threadIdx.x;
  float v = x[row * 256 + tid];
  float s = v * v;
  for (int off = 32; off > 0; off >>= 1) s += __shfl_xor(s, off, 64);
  if ((tid & 63) == 0) red[tid >> 6] = s;
  __syncthreads();
  if (tid == 0) nrm[row] = sqrtf(red[0] + red[1] + red[2] + red[3]);
}

// ---------------- norm-softmax pooling (one block per batch) ---------------
__global__ __launch_bounds__(256) void pool_kernel(
    const float* __restrict__ x, const float* __restrict__ nrm,
    float* __restrict__ pooled, float* __restrict__ pooled_out)
{
  __shared__ float w[512];
  __shared__ float red[4];
  const int b = blockIdx.x, tid = threadIdx.x;
  float n0 = nrm[b * 512 + tid], n1 = nrm[b * 512 + 256 + tid];
  float lm = fmaxf(n0, n1);
  for (int off = 32; off > 0; off >>= 1) lm = fmaxf(lm, __shfl_xor(lm, off, 64));
  if ((tid & 63) == 0) red[tid >> 6] = lm;
  __syncthreads();
  float m = fmaxf(fmaxf(red[0], red[1]), fmaxf(red[2], red[3]));
  float e0 = __expf(n0 - m), e1 = __expf(n1 - m);
  float ls = e0 + e1;
  for (int off = 32; off > 0; off >>= 1) ls += __shfl_xor(ls, off, 64);
  __syncthreads();
  if ((tid & 63) == 0) red[tid >> 6] = ls;
  __syncthreads();
  float inv = 1.f / (red[0] + red[1] + red[2] + red[3]);
  w[tid] = e0 * inv; w[tid + 256] = e1 * inv;
  __syncthreads();
  float acc = 0.f;
  for (int t = 0; t < 512; t++)
    acc += w[t] * x[((size_t)b * 512 + t) * 256 + tid];
  pooled[b * 256 + tid] = acc;
  pooled_out[b * 256 + tid] = acc;
}

// ---------------- FC head (one block per batch) ----------------------------
__global__ __launch_bounds__(256) void fc_head(
    const float* __restrict__ pooled,
    const float* __restrict__ fc1_w, const float* __restrict__ fc1_b,
    const float* __restrict__ fc2_w, const float* __restrict__ fc2_b,
    float* __restrict__ label_out)
{
  __shared__ float pl[256];
  __shared__ float hid[256];
  const int b = blockIdx.x, tid = threadIdx.x;
  pl[tid] = pooled[b * 256 + tid];
  __syncthreads();
  float acc = fc1_b[tid];
  for (int k = 0; k < 256; k++)
    acc += pl[k] * fc1_w[k * 256 + tid];
  hid[tid] = fmaxf(acc, 0.f);
  __syncthreads();
  if (tid < 2) {
    float s = fc2_b[tid];
    for (int k = 0; k < 256; k++)
      s += hid[k] * fc2_w[k * 2 + tid];
    label_out[b * 2 + tid] = s;
  }
}

extern "C" void kernel_launch(void* const* d_in, const int* in_sizes, int n_in,
                              void* d_out, int out_size, void* d_ws, size_t ws_size,
                              hipStream_t stream)
{
  // dict (insertion) order — confirmed: in_sizes[4]==65536 (fc1_w)
  const float* trg   = (const float*)d_in[0];
  const float* src   = (const float*)d_in[1];
  const float* ft_w  = (const float*)d_in[2];
  const float* ft_b  = (const float*)d_in[3];
  const float* fc1_w = (const float*)d_in[4];
  const float* fc1_b = (const float*)d_in[5];
  const float* fc2_w = (const float*)d_in[6];
  const float* fc2_b = (const float*)d_in[7];
  const float* ln_g  = (const float*)d_in[8];
  const float* ln_b  = (const float*)d_in[9];
  const float* pf_w1 = (const float*)d_in[10];
  const float* pf_b1 = (const float*)d_in[11];
  const float* pf_w2 = (const float*)d_in[12];
  const float* pf_b2 = (const float*)d_in[13];
  const float* aw[2][8];  // [sa/ea][wq,bq,wk,bk,wv,bv,wo,bo]
  for (int p = 0; p < 2; p++)
    for (int i = 0; i < 8; i++) aw[p][i] = (const float*)d_in[14 + p * 8 + i];
  float* outp = (float*)d_out;

  float* ws  = (float*)d_ws;
  float* x   = ws;                  // 2M floats
  float* sub = x   + (1u << 21);    // 2M
  float* qb  = sub + (1u << 21);    // 2M
  float* kb  = qb  + (1u << 21);    // 4M
  float* vb  = kb  + (1u << 22);    // 4M  (total 14M floats = 56 MiB)
  float* ob  = qb;                  // alias: attn reads Q to LDS before O write
  float* ffm = kb;                  // alias: kb free during FFN (needs 4M floats)
  float* nrm = vb;                  // alias: vb free after layer loop (8192 floats)
  float* pld = vb + 8192;           // 4096 floats

  const float inv_scale = 0.17677669529663687f;  // 1/sqrt(32)

  // feature transform: x = trg @ ft_w + ft_b
  gemm_bias<false><<<dim3(128, 4), 256, 0, stream>>>(trg, ft_w, ft_b, x, 8192, 256, 64);

  for (int l = 0; l < 2; l++) {
    const size_t wo = (size_t)l * 65536, bo = (size_t)l * 256;
    // ---- self attention ----
    gemm_bias<false><<<dim3(128, 4), 256, 0, stream>>>(x, aw[0][0] + wo, aw[0][1] + bo, qb, 8192, 256, 256);
    gemm_bias<false><<<dim3(128, 4), 256, 0, stream>>>(x, aw[0][2] + wo, aw[0][3] + bo, kb, 8192, 256, 256);
    gemm_bias<false><<<dim3(128, 4), 256, 0, stream>>>(x, aw[0][4] + wo, aw[0][5] + bo, vb, 8192, 256, 256);
    {
      size_t sm = (8 * (512 + 4) + 2304 + 288) * sizeof(float);
      attn_kernel<<<dim3(64, 8, 16), 256, sm, stream>>>(qb, kb, vb, ob, (float*)nullptr, 512, 512, inv_scale);
    }
    gemm_bias<false><<<dim3(128, 4), 256, 0, stream>>>(ob, aw[0][6] + wo, aw[0][7] + bo, sub, 8192, 256, 256);
    residual_ln<<<8192, 256, 0, stream>>>(x, sub, ln_g + bo, ln_b + bo);
    // ---- encoder (cross) attention ----
    gemm_bias<false><<<dim3(128, 4), 256, 0, stream>>>(x, aw[1][0] + wo, aw[1][1] + bo, qb, 8192, 256, 256);
    gemm_bias<false><<<dim3(256, 4), 256, 0, stream>>>(src, aw[1][2] + wo, aw[1][3] + bo, kb, 16384, 256, 256);
    gemm_bias<false><<<dim3(256, 4), 256, 0, stream>>>(src, aw[1][4] + wo, aw[1][5] + bo, vb, 16384, 256, 256);
    {
      size_t sm = (8 * (1024 + 4) + 2304 + 288) * sizeof(float);
      float* att = (l == 1) ? (outp + 4128) : (float*)nullptr;
      attn_kernel<<<dim3(64, 8, 16), 256, sm, stream>>>(qb, kb, vb, ob, att, 512, 1024, inv_scale);
    }
    gemm_bias<false><<<dim3(128, 4), 256, 0, stream>>>(ob, aw[1][6] + wo, aw[1][7] + bo, sub, 8192, 256, 256);
    residual_ln<<<8192, 256, 0, stream>>>(x, sub, ln_g + bo, ln_b + bo);
    // ---- feed forward ----
    gemm_bias<true><<<dim3(128, 8), 256, 0, stream>>>(x, pf_w1 + (size_t)l * 131072, pf_b1 + (size_t)l * 512, ffm, 8192, 512, 256);
    gemm_bias<false><<<dim3(128, 4), 256, 0, stream>>>(ffm, pf_w2 + (size_t)l * 131072, pf_b2 + bo, sub, 8192, 256, 512);
    residual_ln<<<8192, 256, 0, stream>>>(x, sub, ln_g + bo, ln_b + bo);
  }

  // ---- pooling + head ----
  row_norm<<<8192, 256, 0, stream>>>(x, nrm);
  pool_kernel<<<16, 256, 0, stream>>>(x, nrm, pld, outp + 32);
  fc_head<<<16, 256, 0, stream>>>(pld, fc1_w, fc1_b, fc2_w, fc2_b, outp);
}